// Round 5
// baseline (274.473 us; speedup 1.0000x reference)
//
#include <hip/hip_runtime.h>
#include <hip/hip_bf16.h>
#include <math.h>

#define N_NODES   15000
#define N_EDGES   60000
#define EVOCAB    54
#define NODE_INDIM 64
#define EDGE_INDIM 32
#define H  32
#define EH 64
#define N_BOND 4

// setup task ranges (vocab+proj = 535296 = 2091 blocks exact; tail mixed)
#define TASK_VOCAB (EVOCAB * 1024)   // 55296
#define TASK_PROJ  (N_NODES * H)     // 480000
#define TASK_PACK  (3 * H * H)       // 3072
#define TASK_ZDEG  (N_NODES)         // 15000
#define TA (TASK_VOCAB + TASK_PROJ + TASK_PACK + TASK_ZDEG)   // 553368

// ---------------------------------------------------------------------------
// Setup: (a) vocab weight table Wt[v][i][o]  (b) h0 = relu(nf@Wp.T+bp)
// (c) pack GRU weights transposed  (d) zero deg.
// Strided row reads done as float4 (4x fewer load issues on 32-line patterns).
// ---------------------------------------------------------------------------
__global__ void setup_kernel(const int* __restrict__ node_ids,
                             const float* __restrict__ node_table,
                             const float* __restrict__ edge_table,
                             const float* __restrict__ proj_W, const float* __restrict__ proj_b,
                             const float* __restrict__ e1_W1, const float* __restrict__ e1_b1,
                             const float* __restrict__ e1_W2, const float* __restrict__ e1_b2,
                             const float* __restrict__ e2_W1, const float* __restrict__ e2_b1,
                             const float* __restrict__ e2_W2, const float* __restrict__ e2_b2,
                             const float* __restrict__ gWih, const float* __restrict__ gWhh,
                             float* __restrict__ Wt, float* __restrict__ h,
                             float4* __restrict__ Wpk4, float2* __restrict__ Wpk2,
                             int* __restrict__ deg) {
    int t = blockIdx.x * 256 + threadIdx.x;
    if (t >= TA) return;
    if (t < TASK_VOCAB) {
        int v = t >> 10, f = t & 1023, l = t & 63;   // v wave-uniform (1024 % 64 == 0)
        const float* W1 = (v < N_BOND) ? e1_W1 : e2_W1;
        const float* b1 = (v < N_BOND) ? e1_b1 : e2_b1;
        const float* W2 = (v < N_BOND) ? e1_W2 : e2_W2;
        const float* b2 = (v < N_BOND) ? e1_b2 : e2_b2;
        const float4* ef4 = (const float4*)(edge_table + v * EDGE_INDIM);
        // lane l computes z[l]  (EH == 64 == wave size); 128B rows via float4
        const float4* w1r = (const float4*)(W1 + l * EDGE_INDIM);
        float z = b1[l];
        #pragma unroll
        for (int c = 0; c < 8; ++c) {
            float4 e4 = ef4[c], w4 = w1r[c];
            z += e4.x * w4.x + e4.y * w4.y + e4.z * w4.z + e4.w * w4.w;
        }
        z = fmaxf(z, 0.f);
        // output f: dot(z, W2 row f) with z broadcast via wave shfl; 256B row float4
        const float4* w2r = (const float4*)(W2 + f * EH);
        float y = b2[f];
        #pragma unroll
        for (int c = 0; c < 16; ++c) {
            float4 w4 = w2r[c];
            y += __shfl(z, 4 * c,     64) * w4.x;
            y += __shfl(z, 4 * c + 1, 64) * w4.y;
            y += __shfl(z, 4 * c + 2, 64) * w4.z;
            y += __shfl(z, 4 * c + 3, 64) * w4.w;
        }
        Wt[v * 1024 + f] = y;                        // f = i*32 + o
    } else if (t < TASK_VOCAB + TASK_PROJ) {
        int q = t - TASK_VOCAB;
        int n = q >> 5, o = q & 31;
        int gid = node_ids[n];
        const float4* nf4 = (const float4*)(node_table + (size_t)gid * NODE_INDIM);
        const float4* wr4 = (const float4*)(proj_W + o * NODE_INDIM);
        float acc = proj_b[o];
        #pragma unroll
        for (int c = 0; c < 16; ++c) {
            float4 a = nf4[c], w = wr4[c];
            acc += a.x * w.x + a.y * w.y + a.z * w.z + a.w * w.w;
        }
        h[q] = fmaxf(acc, 0.f);
    } else if (t < TASK_VOCAB + TASK_PROJ + TASK_PACK) {
        int q = t - TASK_VOCAB - TASK_PROJ;          // q = j*32 + o
        int j = q >> 5, o = q & 31;
        Wpk4[q] = make_float4(gWih[o * 32 + j], gWih[(32 + o) * 32 + j],
                              gWih[(64 + o) * 32 + j], gWhh[o * 32 + j]);
        Wpk2[q] = make_float2(gWhh[(32 + o) * 32 + j], gWhh[(64 + o) * 32 + j]);
    } else {
        deg[t - TASK_VOCAB - TASK_PROJ - TASK_PACK] = 0;
    }
}

// ---------------------------------------------------------------------------
// CSR build: histogram (+per-edge rank), 1-block scan, scatter.
// ---------------------------------------------------------------------------
__global__ void hist_kernel(const int* __restrict__ dst, int* __restrict__ deg,
                            int* __restrict__ rank) {
    int e = blockIdx.x * 256 + threadIdx.x;
    if (e < N_EDGES) rank[e] = atomicAdd(&deg[dst[e]], 1);
}

__global__ void scan_kernel(const int* __restrict__ deg, int* __restrict__ off) {
    __shared__ int lsum[256];
    int t = threadIdx.x;
    int beg = t * 59, end = min(beg + 59, N_NODES);   // 59*256 = 15104 >= 15000
    int s = 0;
    for (int i = beg; i < end; ++i) s += deg[i];
    lsum[t] = s;
    __syncthreads();
    for (int d2 = 1; d2 < 256; d2 <<= 1) {           // Hillis-Steele inclusive
        int v = (t >= d2) ? lsum[t - d2] : 0;
        __syncthreads();
        lsum[t] += v;
        __syncthreads();
    }
    int run = lsum[t] - s;                           // exclusive base
    if (t == 0) off[0] = 0;
    for (int i = beg; i < end; ++i) { run += deg[i]; off[i + 1] = run; }
}

__global__ void scatter_kernel(const int* __restrict__ dst, const int* __restrict__ off,
                               const int* __restrict__ rank, int* __restrict__ csr) {
    int e = blockIdx.x * 256 + threadIdx.x;
    if (e < N_EDGES) csr[off[dst[e]] + rank[e]] = e;
}

// ---------------------------------------------------------------------------
// Fused step: per-node gather of incoming edges (attention + message),
// local softmax normalization, GRU update. No atomics; ping-pong h buffers.
// 32 lanes per node (o = channel); 2 nodes per wave.
// ---------------------------------------------------------------------------
__launch_bounds__(256)
__global__ void step_kernel(const float* __restrict__ hcur,
                            const int* __restrict__ off, const int* __restrict__ csr,
                            const int* __restrict__ src, const int* __restrict__ edge_ids,
                            const float* __restrict__ Wt, const float* __restrict__ attn_w,
                            const float4* __restrict__ Wpk4, const float2* __restrict__ Wpk2,
                            const float* __restrict__ gbih, const float* __restrict__ gbhh,
                            float* __restrict__ hout) {
    int t = blockIdx.x * 256 + threadIdx.x;          // t < 480000
    int n = t >> 5, o = t & 31;
    float hd  = hcur[n * 32 + o];
    float aw0 = attn_w[o], aw1 = attn_w[32 + o];
    float num = 0.f, den = 0.f;
    int k1 = off[n + 1];
    for (int k = off[n]; k < k1; ++k) {
        int e = csr[k];                              // uniform across the 32-group
        int s = src[e], v = edge_ids[e];
        float hs = hcur[s * 32 + o];                 // coalesced 128B row
        float val = hs * aw0 + hd * aw1;
        #pragma unroll
        for (int m = 16; m > 0; m >>= 1) val += __shfl_xor(val, m, 32);
        float a  = (val > 0.f) ? val : 0.01f * val;  // leaky_relu slope 0.01
        float ex = __expf(a);
        const float* W = Wt + v * 1024 + o;          // column o, lanes coalesced
        float y = 0.f;
        #pragma unroll
        for (int i = 0; i < 32; ++i)
            y += __shfl(hs, i, 32) * W[i * 32];
        num += ex * y;
        den += ex;
    }
    float m = (den > 0.f) ? fmaxf(num / den, 0.f) : 0.f;   // deg-0 -> agg 0
    // --- GRU cell ---
    float gir = 0.f, giz = 0.f, gin = 0.f, ghr = 0.f, ghz = 0.f, ghn = 0.f;
    #pragma unroll 8
    for (int j = 0; j < 32; ++j) {
        float mj = __shfl(m,  j, 32);
        float hj = __shfl(hd, j, 32);
        float4 a4 = Wpk4[j * 32 + o];                // lanes contiguous, wave-broadcast
        float2 b2 = Wpk2[j * 32 + o];
        gir += mj * a4.x;  giz += mj * a4.y;  gin += mj * a4.z;
        ghr += hj * a4.w;  ghz += hj * b2.x;  ghn += hj * b2.y;
    }
    float r  = 1.f / (1.f + __expf(-(gir + gbih[o]      + ghr + gbhh[o])));
    float z  = 1.f / (1.f + __expf(-(giz + gbih[32 + o] + ghz + gbhh[32 + o])));
    float nn = tanhf(gin + gbih[64 + o] + r * (ghn + gbhh[64 + o]));
    hout[t] = (1.f - z) * nn + z * hd;
}

// ---------------------------------------------------------------------------
extern "C" void kernel_launch(void* const* d_in, const int* in_sizes, int n_in,
                              void* d_out, int out_size, void* d_ws, size_t ws_size,
                              hipStream_t stream) {
    const int*   node_ids   = (const int*)d_in[0];
    const int*   edge_ids   = (const int*)d_in[1];
    const int*   src        = (const int*)d_in[2];
    const int*   dst        = (const int*)d_in[3];
    const float* node_table = (const float*)d_in[4];
    const float* edge_table = (const float*)d_in[5];
    const float* proj_W     = (const float*)d_in[6];
    const float* proj_b     = (const float*)d_in[7];
    const float* attn_w     = (const float*)d_in[8];
    const float* e1_W1 = (const float*)d_in[9];  const float* e1_b1 = (const float*)d_in[10];
    const float* e1_W2 = (const float*)d_in[11]; const float* e1_b2 = (const float*)d_in[12];
    const float* e2_W1 = (const float*)d_in[13]; const float* e2_b1 = (const float*)d_in[14];
    const float* e2_W2 = (const float*)d_in[15]; const float* e2_b2 = (const float*)d_in[16];
    const float* gWih  = (const float*)d_in[17]; const float* gWhh  = (const float*)d_in[18];
    const float* gbih  = (const float*)d_in[19]; const float* gbhh  = (const float*)d_in[20];

    // workspace (~4.8 MB): Wt | h_a | h_b | Wpk4 | Wpk2 | deg | off | rank | csr
    char* ws = (char*)d_ws;
    float*  Wt   = (float*)(ws);                     // 221184 B
    float*  h_a  = (float*)(ws + 221184);            // 1920000 B
    float*  h_b  = (float*)(ws + 2141184);           // 1920000 B
    float4* Wpk4 = (float4*)(ws + 4061184);          // 49152 B (16B aligned)
    float2* Wpk2 = (float2*)(ws + 4110336);          // 24576 B
    int*    deg  = (int*)(ws + 4134912);             // 60000 B
    int*    off  = (int*)(ws + 4194912);             // 60004 B
    int*    rank = (int*)(ws + 4254916);             // 240000 B
    int*    csr  = (int*)(ws + 4494916);             // 240000 B
    float*  out  = (float*)d_out;

    setup_kernel<<<(TA + 255) / 256, 256, 0, stream>>>(
        node_ids, node_table, edge_table, proj_W, proj_b,
        e1_W1, e1_b1, e1_W2, e1_b2, e2_W1, e2_b1, e2_W2, e2_b2,
        gWih, gWhh, Wt, h_a, Wpk4, Wpk2, deg);
    hist_kernel<<<(N_EDGES + 255) / 256, 256, 0, stream>>>(dst, deg, rank);
    scan_kernel<<<1, 256, 0, stream>>>(deg, off);
    scatter_kernel<<<(N_EDGES + 255) / 256, 256, 0, stream>>>(dst, off, rank, csr);

    // ping-pong: a -> b -> a -> out
    step_kernel<<<1875, 256, 0, stream>>>(h_a, off, csr, src, edge_ids, Wt, attn_w,
                                          Wpk4, Wpk2, gbih, gbhh, h_b);
    step_kernel<<<1875, 256, 0, stream>>>(h_b, off, csr, src, edge_ids, Wt, attn_w,
                                          Wpk4, Wpk2, gbih, gbhh, h_a);
    step_kernel<<<1875, 256, 0, stream>>>(h_a, off, csr, src, edge_ids, Wt, attn_w,
                                          Wpk4, Wpk2, gbih, gbhh, out);
}